// Round 21
// baseline (74.071 us; speedup 1.0000x reference)
//
#include <hip/hip_runtime.h>
#include <hip/hip_bf16.h>

#define NN 65536   // N*N rows
#define DD 128
#define NH 4
#define HDIM 32

typedef __bf16 bf16_t;
typedef __bf16 bf16x8 __attribute__((ext_vector_type(8)));
typedef __bf16 bf16x4 __attribute__((ext_vector_type(4)));
typedef __bf16 bf16x2 __attribute__((ext_vector_type(2)));
typedef float f32x2 __attribute__((ext_vector_type(2)));
typedef float f32x4 __attribute__((ext_vector_type(4)));
typedef float f32x16 __attribute__((ext_vector_type(16)));
typedef unsigned int u32;
typedef unsigned int u32x4 __attribute__((ext_vector_type(4)));

__device__ inline u32 pk2(float a, float b) {
    bf16x2 t;
    t[0] = (bf16_t)a;
    t[1] = (bf16_t)b;
    return __builtin_bit_cast(u32, t);
}
__device__ inline bf16x8 frag4(u32 a, u32 b, u32 c, u32 d) {
    u32x4 t = {a, b, c, d};
    return __builtin_bit_cast(bf16x8, t);
}
__device__ inline bf16x8 cat44(bf16x4 a, bf16x4 b) {
    bf16x8 r;
#pragma unroll
    for (int j = 0; j < 4; j++) { r[j] = a[j]; r[4 + j] = b[j]; }
    return r;
}
// VERIFIED (R2-R6): pack C-layout (col=lane&31, c=(r&3)+8*(r>>2)+4*hi) into two
// contiguous frags via shfl. f0 = lane's c[hi*8..+8), f1 = c[16+hi*8..+8).
__device__ inline void packX(const f32x16& s, bool lo, bf16x8& f0, bf16x8& f1) {
    u32 wv[8];
#pragma unroll
    for (int g = 0; g < 4; g++) {
        wv[2 * g] = pk2(s[4 * g], s[4 * g + 1]);
        wv[2 * g + 1] = pk2(s[4 * g + 2], s[4 * g + 3]);
    }
    u32 p0 = __shfl_xor(wv[0], 32), p1 = __shfl_xor(wv[1], 32);
    u32 p2 = __shfl_xor(wv[2], 32), p3 = __shfl_xor(wv[3], 32);
    u32 p4 = __shfl_xor(wv[4], 32), p5 = __shfl_xor(wv[5], 32);
    u32 p6 = __shfl_xor(wv[6], 32), p7 = __shfl_xor(wv[7], 32);
    f0 = frag4(lo ? wv[0] : p2, lo ? wv[1] : p3, lo ? p0 : wv[2], lo ? p1 : wv[3]);
    f1 = frag4(lo ? wv[4] : p6, lo ? wv[5] : p7, lo ? p4 : wv[6], lo ? p5 : wv[7]);
}

// ------------- weight conversion to fragment-ready layouts (coalesced reads in hot kernels)
__global__ __launch_bounds__(256) void convw_kernel(const float* __restrict__ Wq,
                                                    const float* __restrict__ Wk,
                                                    const float* __restrict__ Wv,
                                                    const float* __restrict__ Wg,
                                                    const float* __restrict__ Wo,
                                                    bf16_t* __restrict__ wf,
                                                    bf16_t* __restrict__ wfO) {
    __shared__ float Ws[128][33];
    __shared__ float Ws2[128][17];
    int blk = blockIdx.x, t = threadIdx.x;
    if (blk < 16) {
        int m = blk >> 2, h = blk & 3;
        const float* W = (m == 0) ? Wq : (m == 1) ? Wk : (m == 2) ? Wv : Wg;
#pragma unroll
        for (int p = 0; p < 16; p++) {
            int d = p * 8 + (t >> 5), o = t & 31;
            Ws[d][o] = W[d * 128 + h * 32 + o];
        }
        __syncthreads();
        bf16_t* dst = wf + (size_t)blk * 4096;
#pragma unroll
        for (int p = 0; p < 16; p++) {
            int j = p * 256 + t;
            int ks = j >> 9, rsel = (j >> 4) & 31, e = j & 15;
            dst[j] = (bf16_t)Ws[ks * 16 + e][rsel];
        }
    } else {
        int oc = blk - 16;  // 0..7
#pragma unroll
        for (int p = 0; p < 8; p++) {
            int d = p * 16 + (t >> 4), o = t & 15;
            Ws2[d][o] = Wo[d * 128 + oc * 16 + o];
        }
        __syncthreads();
        bf16_t* dst = wfO + (size_t)oc * 2048;
#pragma unroll
        for (int p = 0; p < 8; p++) {
            int j = p * 256 + t;
            int ks = j >> 9, rem = j & 511;
            int lx = rem >> 5, ly = (rem >> 3) & 3, e = j & 7;
            dst[j] = (bf16_t)Ws2[ks * 32 + ly * 8 + e][lx];
        }
    }
}

// ---------------- LayerNorm + bias; z emitted in fragment-ready zF layout ----------------
__global__ __launch_bounds__(256) void ln_kernel(const float* __restrict__ x,
                                                 const float* __restrict__ lw,
                                                 const float* __restrict__ lb,
                                                 const float* __restrict__ Wb,
                                                 bf16_t* __restrict__ zF,
                                                 float* __restrict__ bias3) {
    __shared__ bf16_t zs[4096];        // [ks][rsel][16], 8KB
    __shared__ float bias_s[4][32];
    int t = threadIdx.x;
    int g = t >> 5, l32 = t & 31;
    int rowbase = blockIdx.x * 32;
    int d0 = l32 * 4;
    f32x4 lwv = *reinterpret_cast<const f32x4*>(&lw[d0]);
    f32x4 lbv = *reinterpret_cast<const f32x4*>(&lb[d0]);
    f32x4 wbj[4];
#pragma unroll
    for (int j = 0; j < 4; j++) wbj[j] = *reinterpret_cast<const f32x4*>(&Wb[(d0 + j) * 4]);
#pragma unroll
    for (int r4 = 0; r4 < 4; r4++) {
        int roff = r4 * 8 + g;
        int row = rowbase + roff;
        f32x4 v = *reinterpret_cast<const f32x4*>(&x[(size_t)row * 128 + d0]);
        float s1 = v[0] + v[1] + v[2] + v[3];
        float s2 = v[0] * v[0] + v[1] * v[1] + v[2] * v[2] + v[3] * v[3];
#pragma unroll
        for (int m = 1; m < 32; m <<= 1) {
            s1 += __shfl_xor(s1, m);
            s2 += __shfl_xor(s2, m);
        }
        float mu = s1 * (1.0f / 128.0f);
        float var = s2 * (1.0f / 128.0f) - mu * mu;
        float rs = rsqrtf(var + 1e-5f);
        float zv[4];
        bf16x4 pk;
#pragma unroll
        for (int j = 0; j < 4; j++) {
            zv[j] = (v[j] - mu) * rs * lwv[j] + lbv[j];
            pk[j] = (bf16_t)zv[j];
        }
        *reinterpret_cast<bf16x4*>(&zs[(l32 >> 2) * 512 + roff * 16 + (l32 & 3) * 4]) = pk;
        f32x4 pb = {0.f, 0.f, 0.f, 0.f};
#pragma unroll
        for (int j = 0; j < 4; j++)
#pragma unroll
            for (int hh = 0; hh < 4; hh++) pb[hh] += zv[j] * wbj[j][hh];
#pragma unroll
        for (int m = 1; m < 32; m <<= 1) {
#pragma unroll
            for (int hh = 0; hh < 4; hh++) pb[hh] += __shfl_xor(pb[hh], m);
        }
        if (l32 == 0) {
#pragma unroll
            for (int hh = 0; hh < 4; hh++)
                bias_s[hh][roff] = pb[hh] * 1.4426950408889634f;
        }
    }
    __syncthreads();
    if (t < 128) {
        bias3[(size_t)(t >> 5) * NN + rowbase + (t & 31)] = bias_s[t >> 5][t & 31];
    }
    bf16_t* dst = zF + (size_t)blockIdx.x * 4096;
#pragma unroll
    for (int p = 0; p < 2; p++) {
        int c = p * 2048 + t * 8;
        *reinterpret_cast<bf16x8*>(dst + c) = *reinterpret_cast<bf16x8*>(zs + c);
    }
}

// ---------------- bias transpose: bias2[h][k][q] = bias3[h][q*256+k] ----------------
__global__ __launch_bounds__(256) void biastr_kernel(const float* __restrict__ bias3,
                                                     float* __restrict__ bias2) {
    __shared__ float T[64][68];
    int t = threadIdx.x;
    int h = blockIdx.x >> 4;
    int q0 = ((blockIdx.x >> 2) & 3) * 64, k0 = (blockIdx.x & 3) * 64;
#pragma unroll
    for (int i = 0; i < 4; i++) {
        int id = i * 256 + t;
        int r = id >> 4, cb = id & 15;
        f32x4 val = *reinterpret_cast<const f32x4*>(&bias3[h * NN + (q0 + r) * 256 + k0 + cb * 4]);
        *reinterpret_cast<f32x4*>(&T[r][cb * 4]) = val;
    }
    __syncthreads();
#pragma unroll
    for (int i = 0; i < 4; i++) {
        int id = i * 256 + t;
        int kr = id >> 4, qb = id & 15;
        f32x4 o;
#pragma unroll
        for (int j = 0; j < 4; j++) o[j] = T[qb * 4 + j][kr];
        *reinterpret_cast<f32x4*>(&bias2[h * NN + (k0 + kr) * 256 + q0 + qb * 4]) = o;
    }
}

// ---------- fused QKVG projection + flash attention per (b,h), 8-wave blocks ----------
// Max-free softmax (R19/R20, verified). kt-loop at unroll 2: one extra
// iteration of ILP (QK MFMAs of k+1 under VALU of k) without R19's 8-deep
// live-range explosion. Spill tripwire: fat WRITE_SIZE must stay ~16MB.
__global__ __launch_bounds__(512, 4) void fat_kernel(const bf16_t* __restrict__ zF,
                                                     const bf16_t* __restrict__ wf,
                                                     const float* __restrict__ bias2,
                                                     bf16_t* __restrict__ om2) {
    __shared__ bf16_t Kh[256][44];   // [key][c] padded -> conflict-free b128
    __shared__ bf16_t Vt[32][268];   // [c][key] padded -> 2-way b64 (free)
    int t = threadIdx.x;
    int id = blockIdx.x;
    int h = (id >> 3) & 3;
    int b = (id & 7) + (id >> 5) * 8;
    int w = t >> 6, lane = t & 63;
    int rsel = lane & 31, hi = lane >> 5;
    int hi8 = hi * 8, hi4 = hi * 4;
    bool lo = (hi == 0);
    const float SCL2 = 0.17677669529663687f * 1.4426950408889634f;  // scale * log2(e)
    const bf16_t* zg0 = zF + (size_t)(b * 8 + w) * 4096;  // this wave's 32-row group
    int fro = rsel * 16 + hi8;
    int qpos = w * 32 + rsel;
    const float* bq = bias2 + (size_t)h * NN + qpos;  // + key*256

    // ---- Phase 1: K,V projection (2 accumulators) -> LDS ----
    {
        const bf16_t* wk = wf + (size_t)(1 * 4 + h) * 4096;
        const bf16_t* wv = wf + (size_t)(2 * 4 + h) * 4096;
        f32x16 ak, av;
#pragma unroll
        for (int i = 0; i < 16; i++) { ak[i] = 0.f; av[i] = 0.f; }
#pragma unroll
        for (int ks = 0; ks < 8; ks++) {
            int off = ks * 512 + fro;
            bf16x8 zb = *reinterpret_cast<const bf16x8*>(zg0 + off);
            bf16x8 fk = *reinterpret_cast<const bf16x8*>(wk + off);
            bf16x8 fv = *reinterpret_cast<const bf16x8*>(wv + off);
            ak = __builtin_amdgcn_mfma_f32_32x32x16_bf16(fk, zb, ak, 0, 0, 0);
            av = __builtin_amdgcn_mfma_f32_32x32x16_bf16(fv, zb, av, 0, 0, 0);
        }
        int key0 = w * 32 + rsel;
        bf16x8 f0, f1;
        packX(ak, lo, f0, f1);
        *reinterpret_cast<bf16x8*>(&Kh[key0][hi8]) = f0;
        *reinterpret_cast<bf16x8*>(&Kh[key0][16 + hi8]) = f1;
#pragma unroll
        for (int r = 0; r < 16; r++) {
            int c = (r & 3) + 8 * (r >> 2) + hi4;
            Vt[c][key0] = (bf16_t)av[r];
        }
    }
    __syncthreads();   // K/V visible; Q off the barrier's critical path

    // chunk-0 bias load: overlaps with Q-phase MFMAs
    f32x16 bv;
#pragma unroll
    for (int e = 0; e < 16; e++) {
        int key = 8 * (e >> 2) + hi4 + (e & 3);
        bv[e] = bq[(size_t)key * 256];
    }

    // ---- Phase 2: Q projection only (1 accumulator) ----
    bf16x8 qf0, qf1;
    {
        const bf16_t* wq = wf + (size_t)(0 * 4 + h) * 4096;
        f32x16 aq;
#pragma unroll
        for (int i = 0; i < 16; i++) aq[i] = 0.f;
#pragma unroll
        for (int ks = 0; ks < 8; ks++) {
            int off = ks * 512 + fro;
            bf16x8 zb = *reinterpret_cast<const bf16x8*>(zg0 + off);
            bf16x8 fq = *reinterpret_cast<const bf16x8*>(wq + off);
            aq = __builtin_amdgcn_mfma_f32_32x32x16_bf16(fq, zb, aq, 0, 0, 0);
        }
#pragma unroll
        for (int i = 0; i < 16; i++) aq[i] *= SCL2;
        packX(aq, lo, qf0, qf1);
    }

    // ---- flash attention (max-free): 32 q-rows per wave; s init = bias ----
    f32x16 of;
#pragma unroll
    for (int i = 0; i < 16; i++) of[i] = 0.f;
    float l = 0.f;

#pragma unroll 2
    for (int kt = 0; kt < 8; kt++) {
        bf16x8 k0 = *reinterpret_cast<bf16x8*>(&Kh[kt * 32 + rsel][hi8]);
        bf16x8 k1 = *reinterpret_cast<bf16x8*>(&Kh[kt * 32 + rsel][16 + hi8]);
        __builtin_amdgcn_s_setprio(1);
        f32x16 s = __builtin_amdgcn_mfma_f32_32x32x16_bf16(k0, qf0, bv, 0, 0, 0);
        s = __builtin_amdgcn_mfma_f32_32x32x16_bf16(k1, qf1, s, 0, 0, 0);
        __builtin_amdgcn_s_setprio(0);
        // prefetch next chunk's bias
        if (kt < 7) {
#pragma unroll
            for (int e = 0; e < 16; e++) {
                int key = (kt + 1) * 32 + 8 * (e >> 2) + hi4 + (e & 3);
                bv[e] = bq[(size_t)key * 256];
            }
        }
        // direct exponential (no max subtraction; scores bounded by LN'd inputs)
#pragma unroll
        for (int e = 0; e < 16; e++) s[e] = __builtin_amdgcn_exp2f(s[e]);
        // row sum: packed-f32 tree
        {
            f32x2 a0 = {s[0], s[1]}, a1 = {s[2], s[3]}, a2 = {s[4], s[5]}, a3 = {s[6], s[7]};
            f32x2 a4 = {s[8], s[9]}, a5 = {s[10], s[11]}, a6 = {s[12], s[13]}, a7 = {s[14], s[15]};
            a0 += a1; a2 += a3; a4 += a5; a6 += a7;
            a0 += a2; a4 += a6;
            a0 += a4;
            l += a0[0] + a0[1];
        }
        // P fragments in native C-layout key order (no cross-lane pack)
        bf16x8 pf0 = frag4(pk2(s[0], s[1]), pk2(s[2], s[3]),
                           pk2(s[4], s[5]), pk2(s[6], s[7]));
        bf16x8 pf1 = frag4(pk2(s[8], s[9]), pk2(s[10], s[11]),
                           pk2(s[12], s[13]), pk2(s[14], s[15]));
        // V fragments with the SAME key order: paired b64 reads
        bf16x8 va = cat44(*reinterpret_cast<bf16x4*>(&Vt[rsel][kt * 32 + hi4]),
                          *reinterpret_cast<bf16x4*>(&Vt[rsel][kt * 32 + 8 + hi4]));
        bf16x8 vb = cat44(*reinterpret_cast<bf16x4*>(&Vt[rsel][kt * 32 + 16 + hi4]),
                          *reinterpret_cast<bf16x4*>(&Vt[rsel][kt * 32 + 24 + hi4]));
        __builtin_amdgcn_s_setprio(1);
        of = __builtin_amdgcn_mfma_f32_32x32x16_bf16(va, pf0, of, 0, 0, 0);
        of = __builtin_amdgcn_mfma_f32_32x32x16_bf16(vb, pf1, of, 0, 0, 0);
        __builtin_amdgcn_s_setprio(0);
    }

    l += __shfl_xor(l, 32);
    float linv = 1.0f / l;

    // ---- deferred G projection (1 accumulator), then in-register gating ----
    {
        const bf16_t* wg = wf + (size_t)(3 * 4 + h) * 4096;
        f32x16 ag;
#pragma unroll
        for (int i = 0; i < 16; i++) ag[i] = 0.f;
#pragma unroll
        for (int ks = 0; ks < 8; ks++) {
            int off = ks * 512 + fro;
            bf16x8 zb = *reinterpret_cast<const bf16x8*>(zg0 + off);
            bf16x8 fg = *reinterpret_cast<const bf16x8*>(wg + off);
            ag = __builtin_amdgcn_mfma_f32_32x32x16_bf16(fg, zb, ag, 0, 0, 0);
        }
#pragma unroll
        for (int i = 0; i < 16; i++)
            of[i] = of[i] * linv * (1.0f / (1.0f + __expf(-ag[i])));
    }
    bf16x8 o0, o1;
    packX(of, lo, o0, o1);
    bf16_t* orow = om2 + ((size_t)h * NN + b * 256 + qpos) * 32;
    *reinterpret_cast<bf16x8*>(orow + hi8) = o0;
    *reinterpret_cast<bf16x8*>(orow + 16 + hi8) = o1;
}

// ---------------- final: out = om @ Wo (om pre-gated), fp32 out ----------
// 512 threads / 128 rows per block: half the blocks + barriers of the 256/64 version.
__global__ __launch_bounds__(512) void final_kernel(const bf16_t* __restrict__ om2,
                                                    const bf16_t* __restrict__ wfO,
                                                    float* __restrict__ out) {
    __shared__ __align__(16) char smraw[128 * 136 * 2];  // 34816B; Of aliases exactly
    bf16_t(*As)[136] = reinterpret_cast<bf16_t(*)[136]>(smraw);
    float(*Of)[68] = reinterpret_cast<float(*)[68]>(smraw);
    int t = threadIdx.x;
    int rb = blockIdx.x;   // 512 blocks x 128 rows
#pragma unroll
    for (int i = 0; i < 4; i++) {
        int c = i * 512 + t;
        int r = c >> 4, off = (c & 15) * 8;
        size_t hm = ((size_t)(off >> 5) * NN + rb * 128 + r) * 32 + (off & 31);
        bf16x8 o8 = *reinterpret_cast<const bf16x8*>(&om2[hm]);
        *reinterpret_cast<bf16x8*>(&As[r][off]) = o8;
    }
    __syncthreads();
    int w = t >> 6, lane = t & 63;
    int lx = lane & 15, ly = lane >> 4;
    int m0 = (w >> 1) * 32, n0 = (w & 1) * 32;
    bf16x8 af[2][4];
#pragma unroll
    for (int mt = 0; mt < 2; mt++)
#pragma unroll
        for (int ks = 0; ks < 4; ks++)
            af[mt][ks] = *reinterpret_cast<bf16x8*>(&As[m0 + mt * 16 + lx][ks * 32 + ly * 8]);
    __syncthreads();  // As dead; Of may alias

    for (int half = 0; half < 2; half++) {
        int nc0 = half * 64;
        bf16x8 bfr[2][4];
#pragma unroll
        for (int nt = 0; nt < 2; nt++) {
            int oc = ((nc0 + n0) >> 4) + nt;
#pragma unroll
            for (int ks = 0; ks < 4; ks++)
                bfr[nt][ks] = *reinterpret_cast<const bf16x8*>(
                    &wfO[oc * 2048 + ks * 512 + lx * 32 + ly * 8]);
        }
        f32x4 acc[2][2];
#pragma unroll
        for (int mt = 0; mt < 2; mt++)
#pragma unroll
            for (int nt = 0; nt < 2; nt++) acc[mt][nt] = (f32x4){0.f, 0.f, 0.f, 0.f};
#pragma unroll
        for (int ks = 0; ks < 4; ks++)
#pragma unroll
            for (int mt = 0; mt < 2; mt++)
#pragma unroll
                for (int nt = 0; nt < 2; nt++)
                    acc[mt][nt] = __builtin_amdgcn_mfma_f32_16x16x32_bf16(af[mt][ks], bfr[nt][ks], acc[mt][nt], 0, 0, 0);
#pragma unroll
        for (int mt = 0; mt < 2; mt++)
#pragma unroll
            for (int nt = 0; nt < 2; nt++)
#pragma unroll
                for (int r = 0; r < 4; r++)
                    Of[m0 + mt * 16 + ly * 4 + r][n0 + nt * 16 + lx] = acc[mt][nt][r];
        __syncthreads();
#pragma unroll
        for (int j = 0; j < 4; j++) {
            int ch = j * 512 + t;
            int r = ch >> 4, cb = ch & 15;
            f32x4 val = *reinterpret_cast<f32x4*>(&Of[r][cb * 4]);
            *reinterpret_cast<f32x4*>(&out[(size_t)(rb * 128 + r) * 128 + nc0 + cb * 4]) = val;
        }
        __syncthreads();
    }
}

extern "C" void kernel_launch(void* const* d_in, const int* in_sizes, int n_in,
                              void* d_out, int out_size, void* d_ws, size_t ws_size,
                              hipStream_t stream) {
    const float* x   = (const float*)d_in[0];
    const float* lnw = (const float*)d_in[1];
    const float* lnb = (const float*)d_in[2];
    const float* Wb  = (const float*)d_in[3];
    const float* Wq  = (const float*)d_in[4];
    const float* Wk  = (const float*)d_in[5];
    const float* Wv  = (const float*)d_in[6];
    const float* Wg  = (const float*)d_in[7];
    const float* Wo  = (const float*)d_in[8];
    float* out = (float*)d_out;

    char* ws = (char*)d_ws;
    const size_t MAT = (size_t)NN * 128 * sizeof(bf16_t);  // 16 MB
    bf16_t* zF    = (bf16_t*)(ws);                           // fragment-ready z
    bf16_t* omat  = (bf16_t*)(ws + MAT);                     // head-major, pre-gated
    bf16_t* wf    = (bf16_t*)(ws + 2 * MAT);                 // 16*4096 bf16 = 128KB
    bf16_t* wfO   = (bf16_t*)(ws + 2 * MAT + (128 << 10));   // 8*2048 bf16 = 32KB
    float*  bias3 = (float*)(ws + 2 * MAT + (1 << 20));      // 1MB
    float*  bias2 = (float*)(ws + 2 * MAT + (2 << 20));      // 1MB

    convw_kernel<<<24, 256, 0, stream>>>(Wq, Wk, Wv, Wg, Wo, wf, wfO);
    ln_kernel<<<2048, 256, 0, stream>>>(x, lnw, lnb, Wb, zF, bias3);
    biastr_kernel<<<64, 256, 0, stream>>>(bias3, bias2);
    fat_kernel<<<1024, 512, 0, stream>>>(zF, wf, bias2, omat);
    final_kernel<<<512, 512, 0, stream>>>(omat, wfO, out);
}

// Round 22
// 69.010 us; speedup vs baseline: 1.0733x; 1.0733x over previous
//
#include <hip/hip_runtime.h>
#include <hip/hip_bf16.h>

#define NN 65536   // N*N rows
#define DD 128
#define NH 4
#define HDIM 32

typedef __bf16 bf16_t;
typedef __bf16 bf16x8 __attribute__((ext_vector_type(8)));
typedef __bf16 bf16x4 __attribute__((ext_vector_type(4)));
typedef __bf16 bf16x2 __attribute__((ext_vector_type(2)));
typedef float f32x2 __attribute__((ext_vector_type(2)));
typedef float f32x4 __attribute__((ext_vector_type(4)));
typedef float f32x16 __attribute__((ext_vector_type(16)));
typedef unsigned int u32;
typedef unsigned int u32x4 __attribute__((ext_vector_type(4)));

__device__ inline u32 pk2(float a, float b) {
    bf16x2 t;
    t[0] = (bf16_t)a;
    t[1] = (bf16_t)b;
    return __builtin_bit_cast(u32, t);
}
__device__ inline bf16x8 frag4(u32 a, u32 b, u32 c, u32 d) {
    u32x4 t = {a, b, c, d};
    return __builtin_bit_cast(bf16x8, t);
}
__device__ inline bf16x8 cat44(bf16x4 a, bf16x4 b) {
    bf16x8 r;
#pragma unroll
    for (int j = 0; j < 4; j++) { r[j] = a[j]; r[4 + j] = b[j]; }
    return r;
}
// VERIFIED (R2-R6): pack C-layout (col=lane&31, c=(r&3)+8*(r>>2)+4*hi) into two
// contiguous frags via shfl. f0 = lane's c[hi*8..+8), f1 = c[16+hi*8..+8).
__device__ inline void packX(const f32x16& s, bool lo, bf16x8& f0, bf16x8& f1) {
    u32 wv[8];
#pragma unroll
    for (int g = 0; g < 4; g++) {
        wv[2 * g] = pk2(s[4 * g], s[4 * g + 1]);
        wv[2 * g + 1] = pk2(s[4 * g + 2], s[4 * g + 3]);
    }
    u32 p0 = __shfl_xor(wv[0], 32), p1 = __shfl_xor(wv[1], 32);
    u32 p2 = __shfl_xor(wv[2], 32), p3 = __shfl_xor(wv[3], 32);
    u32 p4 = __shfl_xor(wv[4], 32), p5 = __shfl_xor(wv[5], 32);
    u32 p6 = __shfl_xor(wv[6], 32), p7 = __shfl_xor(wv[7], 32);
    f0 = frag4(lo ? wv[0] : p2, lo ? wv[1] : p3, lo ? p0 : wv[2], lo ? p1 : wv[3]);
    f1 = frag4(lo ? wv[4] : p6, lo ? wv[5] : p7, lo ? p4 : wv[6], lo ? p5 : wv[7]);
}

// ------- merged prep kernel: blocks 0..23 = weight conversion; 24..2071 = LayerNorm -------
// LDS is a 16.9KB union arena (convw Ws branch is the largest user).
__global__ __launch_bounds__(256) void prep_kernel(const float* __restrict__ x,
                                                   const float* __restrict__ lw,
                                                   const float* __restrict__ lb,
                                                   const float* __restrict__ Wb,
                                                   const float* __restrict__ Wq,
                                                   const float* __restrict__ Wk,
                                                   const float* __restrict__ Wv,
                                                   const float* __restrict__ Wg,
                                                   const float* __restrict__ Wo,
                                                   bf16_t* __restrict__ wf,
                                                   bf16_t* __restrict__ wfO,
                                                   bf16_t* __restrict__ zF,
                                                   float* __restrict__ bias3) {
    __shared__ __align__(16) char arena[16896];
    int blk = blockIdx.x, t = threadIdx.x;
    if (blk < 16) {
        float(*Ws)[33] = reinterpret_cast<float(*)[33]>(arena);
        int m = blk >> 2, h = blk & 3;
        const float* W = (m == 0) ? Wq : (m == 1) ? Wk : (m == 2) ? Wv : Wg;
#pragma unroll
        for (int p = 0; p < 16; p++) {
            int d = p * 8 + (t >> 5), o = t & 31;
            Ws[d][o] = W[d * 128 + h * 32 + o];
        }
        __syncthreads();
        bf16_t* dst = wf + (size_t)blk * 4096;
#pragma unroll
        for (int p = 0; p < 16; p++) {
            int j = p * 256 + t;
            int ks = j >> 9, rsel = (j >> 4) & 31, e = j & 15;
            dst[j] = (bf16_t)Ws[ks * 16 + e][rsel];
        }
        return;
    }
    if (blk < 24) {
        float(*Ws2)[17] = reinterpret_cast<float(*)[17]>(arena);
        int oc = blk - 16;  // 0..7
#pragma unroll
        for (int p = 0; p < 8; p++) {
            int d = p * 16 + (t >> 4), o = t & 15;
            Ws2[d][o] = Wo[d * 128 + oc * 16 + o];
        }
        __syncthreads();
        bf16_t* dst = wfO + (size_t)oc * 2048;
#pragma unroll
        for (int p = 0; p < 8; p++) {
            int j = p * 256 + t;
            int ks = j >> 9, rem = j & 511;
            int lx = rem >> 5, ly = (rem >> 3) & 3, e = j & 7;
            dst[j] = (bf16_t)Ws2[ks * 32 + ly * 8 + e][lx];
        }
        return;
    }
    // ---- LayerNorm + fused bias; z emitted in fragment-ready zF layout ----
    bf16_t* zs = reinterpret_cast<bf16_t*>(arena);            // 8KB [ks][rsel][16]
    float(*bias_s)[32] = reinterpret_cast<float(*)[32]>(arena + 8192);
    int lblk = blk - 24;
    int g = t >> 5, l32 = t & 31;
    int rowbase = lblk * 32;
    int d0 = l32 * 4;
    f32x4 lwv = *reinterpret_cast<const f32x4*>(&lw[d0]);
    f32x4 lbv = *reinterpret_cast<const f32x4*>(&lb[d0]);
    f32x4 wbj[4];
#pragma unroll
    for (int j = 0; j < 4; j++) wbj[j] = *reinterpret_cast<const f32x4*>(&Wb[(d0 + j) * 4]);
#pragma unroll
    for (int r4 = 0; r4 < 4; r4++) {
        int roff = r4 * 8 + g;
        int row = rowbase + roff;
        f32x4 v = *reinterpret_cast<const f32x4*>(&x[(size_t)row * 128 + d0]);
        float s1 = v[0] + v[1] + v[2] + v[3];
        float s2 = v[0] * v[0] + v[1] * v[1] + v[2] * v[2] + v[3] * v[3];
#pragma unroll
        for (int m = 1; m < 32; m <<= 1) {
            s1 += __shfl_xor(s1, m);
            s2 += __shfl_xor(s2, m);
        }
        float mu = s1 * (1.0f / 128.0f);
        float var = s2 * (1.0f / 128.0f) - mu * mu;
        float rs = rsqrtf(var + 1e-5f);
        float zv[4];
        bf16x4 pk;
#pragma unroll
        for (int j = 0; j < 4; j++) {
            zv[j] = (v[j] - mu) * rs * lwv[j] + lbv[j];
            pk[j] = (bf16_t)zv[j];
        }
        *reinterpret_cast<bf16x4*>(&zs[(l32 >> 2) * 512 + roff * 16 + (l32 & 3) * 4]) = pk;
        f32x4 pb = {0.f, 0.f, 0.f, 0.f};
#pragma unroll
        for (int j = 0; j < 4; j++)
#pragma unroll
            for (int hh = 0; hh < 4; hh++) pb[hh] += zv[j] * wbj[j][hh];
#pragma unroll
        for (int m = 1; m < 32; m <<= 1) {
#pragma unroll
            for (int hh = 0; hh < 4; hh++) pb[hh] += __shfl_xor(pb[hh], m);
        }
        if (l32 == 0) {
#pragma unroll
            for (int hh = 0; hh < 4; hh++)
                bias_s[hh][roff] = pb[hh] * 1.4426950408889634f;
        }
    }
    __syncthreads();
    if (t < 128) {
        bias3[(size_t)(t >> 5) * NN + rowbase + (t & 31)] = bias_s[t >> 5][t & 31];
    }
    bf16_t* dst = zF + (size_t)lblk * 4096;
#pragma unroll
    for (int p = 0; p < 2; p++) {
        int c = p * 2048 + t * 8;
        *reinterpret_cast<bf16x8*>(dst + c) = *reinterpret_cast<bf16x8*>(zs + c);
    }
}

// ---------------- bias transpose: bias2[h][k][q] = bias3[h][q*256+k] ----------------
__global__ __launch_bounds__(256) void biastr_kernel(const float* __restrict__ bias3,
                                                     float* __restrict__ bias2) {
    __shared__ float T[64][68];
    int t = threadIdx.x;
    int h = blockIdx.x >> 4;
    int q0 = ((blockIdx.x >> 2) & 3) * 64, k0 = (blockIdx.x & 3) * 64;
#pragma unroll
    for (int i = 0; i < 4; i++) {
        int id = i * 256 + t;
        int r = id >> 4, cb = id & 15;
        f32x4 val = *reinterpret_cast<const f32x4*>(&bias3[h * NN + (q0 + r) * 256 + k0 + cb * 4]);
        *reinterpret_cast<f32x4*>(&T[r][cb * 4]) = val;
    }
    __syncthreads();
#pragma unroll
    for (int i = 0; i < 4; i++) {
        int id = i * 256 + t;
        int kr = id >> 4, qb = id & 15;
        f32x4 o;
#pragma unroll
        for (int j = 0; j < 4; j++) o[j] = T[qb * 4 + j][kr];
        *reinterpret_cast<f32x4*>(&bias2[h * NN + (k0 + kr) * 256 + q0 + qb * 4]) = o;
    }
}

// ---------- fused QKVG projection + flash attention per (b,h), 8-wave blocks ----------
// R20 config (best): max-free softmax, kt-loop at unroll 1 (unroll>=2 lets the
// scheduler overlap live ranges -> spill, R19/R21).
__global__ __launch_bounds__(512, 4) void fat_kernel(const bf16_t* __restrict__ zF,
                                                     const bf16_t* __restrict__ wf,
                                                     const float* __restrict__ bias2,
                                                     bf16_t* __restrict__ om2) {
    __shared__ bf16_t Kh[256][44];   // [key][c] padded -> conflict-free b128
    __shared__ bf16_t Vt[32][268];   // [c][key] padded -> 2-way b64 (free)
    int t = threadIdx.x;
    int id = blockIdx.x;
    int h = (id >> 3) & 3;
    int b = (id & 7) + (id >> 5) * 8;
    int w = t >> 6, lane = t & 63;
    int rsel = lane & 31, hi = lane >> 5;
    int hi8 = hi * 8, hi4 = hi * 4;
    bool lo = (hi == 0);
    const float SCL2 = 0.17677669529663687f * 1.4426950408889634f;  // scale * log2(e)
    const bf16_t* zg0 = zF + (size_t)(b * 8 + w) * 4096;  // this wave's 32-row group
    int fro = rsel * 16 + hi8;
    int qpos = w * 32 + rsel;
    const float* bq = bias2 + (size_t)h * NN + qpos;  // + key*256

    // ---- Phase 1: K,V projection (2 accumulators) -> LDS ----
    {
        const bf16_t* wk = wf + (size_t)(1 * 4 + h) * 4096;
        const bf16_t* wv = wf + (size_t)(2 * 4 + h) * 4096;
        f32x16 ak, av;
#pragma unroll
        for (int i = 0; i < 16; i++) { ak[i] = 0.f; av[i] = 0.f; }
#pragma unroll
        for (int ks = 0; ks < 8; ks++) {
            int off = ks * 512 + fro;
            bf16x8 zb = *reinterpret_cast<const bf16x8*>(zg0 + off);
            bf16x8 fk = *reinterpret_cast<const bf16x8*>(wk + off);
            bf16x8 fv = *reinterpret_cast<const bf16x8*>(wv + off);
            ak = __builtin_amdgcn_mfma_f32_32x32x16_bf16(fk, zb, ak, 0, 0, 0);
            av = __builtin_amdgcn_mfma_f32_32x32x16_bf16(fv, zb, av, 0, 0, 0);
        }
        int key0 = w * 32 + rsel;
        bf16x8 f0, f1;
        packX(ak, lo, f0, f1);
        *reinterpret_cast<bf16x8*>(&Kh[key0][hi8]) = f0;
        *reinterpret_cast<bf16x8*>(&Kh[key0][16 + hi8]) = f1;
#pragma unroll
        for (int r = 0; r < 16; r++) {
            int c = (r & 3) + 8 * (r >> 2) + hi4;
            Vt[c][key0] = (bf16_t)av[r];
        }
    }
    __syncthreads();   // K/V visible; Q off the barrier's critical path

    // chunk-0 bias load: overlaps with Q-phase MFMAs
    f32x16 bv;
#pragma unroll
    for (int e = 0; e < 16; e++) {
        int key = 8 * (e >> 2) + hi4 + (e & 3);
        bv[e] = bq[(size_t)key * 256];
    }

    // ---- Phase 2: Q projection only (1 accumulator) ----
    bf16x8 qf0, qf1;
    {
        const bf16_t* wq = wf + (size_t)(0 * 4 + h) * 4096;
        f32x16 aq;
#pragma unroll
        for (int i = 0; i < 16; i++) aq[i] = 0.f;
#pragma unroll
        for (int ks = 0; ks < 8; ks++) {
            int off = ks * 512 + fro;
            bf16x8 zb = *reinterpret_cast<const bf16x8*>(zg0 + off);
            bf16x8 fq = *reinterpret_cast<const bf16x8*>(wq + off);
            aq = __builtin_amdgcn_mfma_f32_32x32x16_bf16(fq, zb, aq, 0, 0, 0);
        }
#pragma unroll
        for (int i = 0; i < 16; i++) aq[i] *= SCL2;
        packX(aq, lo, qf0, qf1);
    }

    // ---- flash attention (max-free): 32 q-rows per wave; s init = bias ----
    f32x16 of;
#pragma unroll
    for (int i = 0; i < 16; i++) of[i] = 0.f;
    float l = 0.f;

#pragma unroll 1
    for (int kt = 0; kt < 8; kt++) {
        bf16x8 k0 = *reinterpret_cast<bf16x8*>(&Kh[kt * 32 + rsel][hi8]);
        bf16x8 k1 = *reinterpret_cast<bf16x8*>(&Kh[kt * 32 + rsel][16 + hi8]);
        __builtin_amdgcn_s_setprio(1);
        f32x16 s = __builtin_amdgcn_mfma_f32_32x32x16_bf16(k0, qf0, bv, 0, 0, 0);
        s = __builtin_amdgcn_mfma_f32_32x32x16_bf16(k1, qf1, s, 0, 0, 0);
        __builtin_amdgcn_s_setprio(0);
        // prefetch next chunk's bias
        if (kt < 7) {
#pragma unroll
            for (int e = 0; e < 16; e++) {
                int key = (kt + 1) * 32 + 8 * (e >> 2) + hi4 + (e & 3);
                bv[e] = bq[(size_t)key * 256];
            }
        }
        // direct exponential (no max subtraction; scores bounded by LN'd inputs)
#pragma unroll
        for (int e = 0; e < 16; e++) s[e] = __builtin_amdgcn_exp2f(s[e]);
        // row sum: packed-f32 tree
        {
            f32x2 a0 = {s[0], s[1]}, a1 = {s[2], s[3]}, a2 = {s[4], s[5]}, a3 = {s[6], s[7]};
            f32x2 a4 = {s[8], s[9]}, a5 = {s[10], s[11]}, a6 = {s[12], s[13]}, a7 = {s[14], s[15]};
            a0 += a1; a2 += a3; a4 += a5; a6 += a7;
            a0 += a2; a4 += a6;
            a0 += a4;
            l += a0[0] + a0[1];
        }
        // P fragments in native C-layout key order (no cross-lane pack)
        bf16x8 pf0 = frag4(pk2(s[0], s[1]), pk2(s[2], s[3]),
                           pk2(s[4], s[5]), pk2(s[6], s[7]));
        bf16x8 pf1 = frag4(pk2(s[8], s[9]), pk2(s[10], s[11]),
                           pk2(s[12], s[13]), pk2(s[14], s[15]));
        // V fragments with the SAME key order: paired b64 reads
        bf16x8 va = cat44(*reinterpret_cast<bf16x4*>(&Vt[rsel][kt * 32 + hi4]),
                          *reinterpret_cast<bf16x4*>(&Vt[rsel][kt * 32 + 8 + hi4]));
        bf16x8 vb = cat44(*reinterpret_cast<bf16x4*>(&Vt[rsel][kt * 32 + 16 + hi4]),
                          *reinterpret_cast<bf16x4*>(&Vt[rsel][kt * 32 + 24 + hi4]));
        __builtin_amdgcn_s_setprio(1);
        of = __builtin_amdgcn_mfma_f32_32x32x16_bf16(va, pf0, of, 0, 0, 0);
        of = __builtin_amdgcn_mfma_f32_32x32x16_bf16(vb, pf1, of, 0, 0, 0);
        __builtin_amdgcn_s_setprio(0);
    }

    l += __shfl_xor(l, 32);
    float linv = 1.0f / l;

    // ---- deferred G projection (1 accumulator), then in-register gating ----
    {
        const bf16_t* wg = wf + (size_t)(3 * 4 + h) * 4096;
        f32x16 ag;
#pragma unroll
        for (int i = 0; i < 16; i++) ag[i] = 0.f;
#pragma unroll
        for (int ks = 0; ks < 8; ks++) {
            int off = ks * 512 + fro;
            bf16x8 zb = *reinterpret_cast<const bf16x8*>(zg0 + off);
            bf16x8 fg = *reinterpret_cast<const bf16x8*>(wg + off);
            ag = __builtin_amdgcn_mfma_f32_32x32x16_bf16(fg, zb, ag, 0, 0, 0);
        }
#pragma unroll
        for (int i = 0; i < 16; i++)
            of[i] = of[i] * linv * (1.0f / (1.0f + __expf(-ag[i])));
    }
    bf16x8 o0, o1;
    packX(of, lo, o0, o1);
    bf16_t* orow = om2 + ((size_t)h * NN + b * 256 + qpos) * 32;
    *reinterpret_cast<bf16x8*>(orow + hi8) = o0;
    *reinterpret_cast<bf16x8*>(orow + 16 + hi8) = o1;
}

// ---------------- final: out = om @ Wo (om pre-gated), fp32 out ----------
__global__ __launch_bounds__(256) void final_kernel(const bf16_t* __restrict__ om2,
                                                    const bf16_t* __restrict__ wfO,
                                                    float* __restrict__ out) {
    __shared__ __align__(16) char smraw[64 * 136 * 2];
    bf16_t(*As)[136] = reinterpret_cast<bf16_t(*)[136]>(smraw);
    float(*Of)[68] = reinterpret_cast<float(*)[68]>(smraw);
    int t = threadIdx.x;
    int rb = blockIdx.x;
#pragma unroll
    for (int i = 0; i < 4; i++) {
        int c = i * 256 + t;
        int r = c >> 4, off = (c & 15) * 8;
        size_t hm = ((size_t)(off >> 5) * NN + rb * 64 + r) * 32 + (off & 31);
        bf16x8 o8 = *reinterpret_cast<const bf16x8*>(&om2[hm]);
        *reinterpret_cast<bf16x8*>(&As[r][off]) = o8;
    }
    __syncthreads();
    int w = t >> 6, lane = t & 63;
    int lx = lane & 15, ly = lane >> 4;
    int m0 = (w >> 1) * 32, n0 = (w & 1) * 32;
    bf16x8 af[2][4];
#pragma unroll
    for (int mt = 0; mt < 2; mt++)
#pragma unroll
        for (int ks = 0; ks < 4; ks++)
            af[mt][ks] = *reinterpret_cast<bf16x8*>(&As[m0 + mt * 16 + lx][ks * 32 + ly * 8]);
    __syncthreads();  // As dead; Of may alias

    for (int half = 0; half < 2; half++) {
        int nc0 = half * 64;
        bf16x8 bfr[2][4];
#pragma unroll
        for (int nt = 0; nt < 2; nt++) {
            int oc = ((nc0 + n0) >> 4) + nt;
#pragma unroll
            for (int ks = 0; ks < 4; ks++)
                bfr[nt][ks] = *reinterpret_cast<const bf16x8*>(
                    &wfO[oc * 2048 + ks * 512 + lx * 32 + ly * 8]);
        }
        f32x4 acc[2][2];
#pragma unroll
        for (int mt = 0; mt < 2; mt++)
#pragma unroll
            for (int nt = 0; nt < 2; nt++) acc[mt][nt] = (f32x4){0.f, 0.f, 0.f, 0.f};
#pragma unroll
        for (int ks = 0; ks < 4; ks++)
#pragma unroll
            for (int mt = 0; mt < 2; mt++)
#pragma unroll
                for (int nt = 0; nt < 2; nt++)
                    acc[mt][nt] = __builtin_amdgcn_mfma_f32_16x16x32_bf16(af[mt][ks], bfr[nt][ks], acc[mt][nt], 0, 0, 0);
#pragma unroll
        for (int mt = 0; mt < 2; mt++)
#pragma unroll
            for (int nt = 0; nt < 2; nt++)
#pragma unroll
                for (int r = 0; r < 4; r++)
                    Of[m0 + mt * 16 + ly * 4 + r][n0 + nt * 16 + lx] = acc[mt][nt][r];
        __syncthreads();
#pragma unroll
        for (int j = 0; j < 4; j++) {
            int ch = j * 256 + t;
            int r = ch >> 4, cb = ch & 15;
            f32x4 val = *reinterpret_cast<f32x4*>(&Of[r][cb * 4]);
            *reinterpret_cast<f32x4*>(&out[(rb * 64 + r) * 128 + nc0 + cb * 4]) = val;
        }
        __syncthreads();
    }
}

extern "C" void kernel_launch(void* const* d_in, const int* in_sizes, int n_in,
                              void* d_out, int out_size, void* d_ws, size_t ws_size,
                              hipStream_t stream) {
    const float* x   = (const float*)d_in[0];
    const float* lnw = (const float*)d_in[1];
    const float* lnb = (const float*)d_in[2];
    const float* Wb  = (const float*)d_in[3];
    const float* Wq  = (const float*)d_in[4];
    const float* Wk  = (const float*)d_in[5];
    const float* Wv  = (const float*)d_in[6];
    const float* Wg  = (const float*)d_in[7];
    const float* Wo  = (const float*)d_in[8];
    float* out = (float*)d_out;

    char* ws = (char*)d_ws;
    const size_t MAT = (size_t)NN * 128 * sizeof(bf16_t);  // 16 MB
    bf16_t* zF    = (bf16_t*)(ws);                           // fragment-ready z
    bf16_t* omat  = (bf16_t*)(ws + MAT);                     // head-major, pre-gated
    bf16_t* wf    = (bf16_t*)(ws + 2 * MAT);                 // 16*4096 bf16 = 128KB
    bf16_t* wfO   = (bf16_t*)(ws + 2 * MAT + (128 << 10));   // 8*2048 bf16 = 32KB
    float*  bias3 = (float*)(ws + 2 * MAT + (1 << 20));      // 1MB
    float*  bias2 = (float*)(ws + 2 * MAT + (2 << 20));      // 1MB

    prep_kernel<<<2072, 256, 0, stream>>>(x, lnw, lnb, Wb, Wq, Wk, Wv, Wg, Wo,
                                          wf, wfO, zF, bias3);
    biastr_kernel<<<64, 256, 0, stream>>>(bias3, bias2);
    fat_kernel<<<1024, 512, 0, stream>>>(zF, wf, bias2, omat);
    final_kernel<<<1024, 256, 0, stream>>>(omat, wfO, out);
}

// Round 23
// 66.041 us; speedup vs baseline: 1.1216x; 1.0450x over previous
//
#include <hip/hip_runtime.h>
#include <hip/hip_bf16.h>

#define NN 65536   // N*N rows
#define DD 128
#define NH 4
#define HDIM 32

typedef __bf16 bf16_t;
typedef __bf16 bf16x8 __attribute__((ext_vector_type(8)));
typedef __bf16 bf16x4 __attribute__((ext_vector_type(4)));
typedef __bf16 bf16x2 __attribute__((ext_vector_type(2)));
typedef float f32x2 __attribute__((ext_vector_type(2)));
typedef float f32x4 __attribute__((ext_vector_type(4)));
typedef float f32x16 __attribute__((ext_vector_type(16)));
typedef unsigned int u32;
typedef unsigned int u32x4 __attribute__((ext_vector_type(4)));

__device__ inline u32 pk2(float a, float b) {
    bf16x2 t;
    t[0] = (bf16_t)a;
    t[1] = (bf16_t)b;
    return __builtin_bit_cast(u32, t);
}
__device__ inline bf16x8 frag4(u32 a, u32 b, u32 c, u32 d) {
    u32x4 t = {a, b, c, d};
    return __builtin_bit_cast(bf16x8, t);
}
__device__ inline bf16x8 cat44(bf16x4 a, bf16x4 b) {
    bf16x8 r;
#pragma unroll
    for (int j = 0; j < 4; j++) { r[j] = a[j]; r[4 + j] = b[j]; }
    return r;
}
// VERIFIED (R2-R6): pack C-layout (col=lane&31, c=(r&3)+8*(r>>2)+4*hi) into two
// contiguous frags via shfl. f0 = lane's c[hi*8..+8), f1 = c[16+hi*8..+8).
__device__ inline void packX(const f32x16& s, bool lo, bf16x8& f0, bf16x8& f1) {
    u32 wv[8];
#pragma unroll
    for (int g = 0; g < 4; g++) {
        wv[2 * g] = pk2(s[4 * g], s[4 * g + 1]);
        wv[2 * g + 1] = pk2(s[4 * g + 2], s[4 * g + 3]);
    }
    u32 p0 = __shfl_xor(wv[0], 32), p1 = __shfl_xor(wv[1], 32);
    u32 p2 = __shfl_xor(wv[2], 32), p3 = __shfl_xor(wv[3], 32);
    u32 p4 = __shfl_xor(wv[4], 32), p5 = __shfl_xor(wv[5], 32);
    u32 p6 = __shfl_xor(wv[6], 32), p7 = __shfl_xor(wv[7], 32);
    f0 = frag4(lo ? wv[0] : p2, lo ? wv[1] : p3, lo ? p0 : wv[2], lo ? p1 : wv[3]);
    f1 = frag4(lo ? wv[4] : p6, lo ? wv[5] : p7, lo ? p4 : wv[6], lo ? p5 : wv[7]);
}

// ------- merged prep kernel: blocks 0..23 = weight conversion; 24..2071 = LayerNorm -------
// LN branch writes bias2[h][k][q] DIRECTLY (q = lblk>>3 fixed per block,
// k = (lblk&7)*32 + rl): 128 scalar L2 stores per block replaces the whole
// biastr kernel + bias3 buffer.
__global__ __launch_bounds__(256) void prep_kernel(const float* __restrict__ x,
                                                   const float* __restrict__ lw,
                                                   const float* __restrict__ lb,
                                                   const float* __restrict__ Wb,
                                                   const float* __restrict__ Wq,
                                                   const float* __restrict__ Wk,
                                                   const float* __restrict__ Wv,
                                                   const float* __restrict__ Wg,
                                                   const float* __restrict__ Wo,
                                                   bf16_t* __restrict__ wf,
                                                   bf16_t* __restrict__ wfO,
                                                   bf16_t* __restrict__ zF,
                                                   float* __restrict__ bias2) {
    __shared__ __align__(16) char arena[16896];
    int blk = blockIdx.x, t = threadIdx.x;
    if (blk < 16) {
        float(*Ws)[33] = reinterpret_cast<float(*)[33]>(arena);
        int m = blk >> 2, h = blk & 3;
        const float* W = (m == 0) ? Wq : (m == 1) ? Wk : (m == 2) ? Wv : Wg;
#pragma unroll
        for (int p = 0; p < 16; p++) {
            int d = p * 8 + (t >> 5), o = t & 31;
            Ws[d][o] = W[d * 128 + h * 32 + o];
        }
        __syncthreads();
        bf16_t* dst = wf + (size_t)blk * 4096;
#pragma unroll
        for (int p = 0; p < 16; p++) {
            int j = p * 256 + t;
            int ks = j >> 9, rsel = (j >> 4) & 31, e = j & 15;
            dst[j] = (bf16_t)Ws[ks * 16 + e][rsel];
        }
        return;
    }
    if (blk < 24) {
        float(*Ws2)[17] = reinterpret_cast<float(*)[17]>(arena);
        int oc = blk - 16;  // 0..7
#pragma unroll
        for (int p = 0; p < 8; p++) {
            int d = p * 16 + (t >> 4), o = t & 15;
            Ws2[d][o] = Wo[d * 128 + oc * 16 + o];
        }
        __syncthreads();
        bf16_t* dst = wfO + (size_t)oc * 2048;
#pragma unroll
        for (int p = 0; p < 8; p++) {
            int j = p * 256 + t;
            int ks = j >> 9, rem = j & 511;
            int lx = rem >> 5, ly = (rem >> 3) & 3, e = j & 7;
            dst[j] = (bf16_t)Ws2[ks * 32 + ly * 8 + e][lx];
        }
        return;
    }
    // ---- LayerNorm + fused bias; z emitted in fragment-ready zF layout ----
    bf16_t* zs = reinterpret_cast<bf16_t*>(arena);            // 8KB [ks][rsel][16]
    float(*bias_s)[32] = reinterpret_cast<float(*)[32]>(arena + 8192);
    int lblk = blk - 24;
    int g = t >> 5, l32 = t & 31;
    int rowbase = lblk * 32;
    int d0 = l32 * 4;
    f32x4 lwv = *reinterpret_cast<const f32x4*>(&lw[d0]);
    f32x4 lbv = *reinterpret_cast<const f32x4*>(&lb[d0]);
    f32x4 wbj[4];
#pragma unroll
    for (int j = 0; j < 4; j++) wbj[j] = *reinterpret_cast<const f32x4*>(&Wb[(d0 + j) * 4]);
#pragma unroll
    for (int r4 = 0; r4 < 4; r4++) {
        int roff = r4 * 8 + g;
        int row = rowbase + roff;
        f32x4 v = *reinterpret_cast<const f32x4*>(&x[(size_t)row * 128 + d0]);
        float s1 = v[0] + v[1] + v[2] + v[3];
        float s2 = v[0] * v[0] + v[1] * v[1] + v[2] * v[2] + v[3] * v[3];
#pragma unroll
        for (int m = 1; m < 32; m <<= 1) {
            s1 += __shfl_xor(s1, m);
            s2 += __shfl_xor(s2, m);
        }
        float mu = s1 * (1.0f / 128.0f);
        float var = s2 * (1.0f / 128.0f) - mu * mu;
        float rs = rsqrtf(var + 1e-5f);
        float zv[4];
        bf16x4 pk;
#pragma unroll
        for (int j = 0; j < 4; j++) {
            zv[j] = (v[j] - mu) * rs * lwv[j] + lbv[j];
            pk[j] = (bf16_t)zv[j];
        }
        *reinterpret_cast<bf16x4*>(&zs[(l32 >> 2) * 512 + roff * 16 + (l32 & 3) * 4]) = pk;
        f32x4 pb = {0.f, 0.f, 0.f, 0.f};
#pragma unroll
        for (int j = 0; j < 4; j++)
#pragma unroll
            for (int hh = 0; hh < 4; hh++) pb[hh] += zv[j] * wbj[j][hh];
#pragma unroll
        for (int m = 1; m < 32; m <<= 1) {
#pragma unroll
            for (int hh = 0; hh < 4; hh++) pb[hh] += __shfl_xor(pb[hh], m);
        }
        if (l32 == 0) {
#pragma unroll
            for (int hh = 0; hh < 4; hh++)
                bias_s[hh][roff] = pb[hh] * 1.4426950408889634f;
        }
    }
    __syncthreads();
    if (t < 128) {
        // direct transposed write: bias2[h][k][q], q fixed per block
        int hh = t >> 5, rl = t & 31;
        int q = lblk >> 3, k = ((lblk & 7) << 5) + rl;
        bias2[(size_t)hh * NN + (size_t)k * 256 + q] = bias_s[hh][rl];
    }
    bf16_t* dst = zF + (size_t)lblk * 4096;
#pragma unroll
    for (int p = 0; p < 2; p++) {
        int c = p * 2048 + t * 8;
        *reinterpret_cast<bf16x8*>(dst + c) = *reinterpret_cast<bf16x8*>(zs + c);
    }
}

// ---------- fused QKVG projection + flash attention per (b,h), 8-wave blocks ----------
// R20 config (best): max-free softmax, kt-loop at unroll 1 (unroll>=2 lets the
// scheduler overlap live ranges -> spill, R19/R21).
__global__ __launch_bounds__(512, 4) void fat_kernel(const bf16_t* __restrict__ zF,
                                                     const bf16_t* __restrict__ wf,
                                                     const float* __restrict__ bias2,
                                                     bf16_t* __restrict__ om2) {
    __shared__ bf16_t Kh[256][44];   // [key][c] padded -> conflict-free b128
    __shared__ bf16_t Vt[32][268];   // [c][key] padded -> 2-way b64 (free)
    int t = threadIdx.x;
    int id = blockIdx.x;
    int h = (id >> 3) & 3;
    int b = (id & 7) + (id >> 5) * 8;
    int w = t >> 6, lane = t & 63;
    int rsel = lane & 31, hi = lane >> 5;
    int hi8 = hi * 8, hi4 = hi * 4;
    bool lo = (hi == 0);
    const float SCL2 = 0.17677669529663687f * 1.4426950408889634f;  // scale * log2(e)
    const bf16_t* zg0 = zF + (size_t)(b * 8 + w) * 4096;  // this wave's 32-row group
    int fro = rsel * 16 + hi8;
    int qpos = w * 32 + rsel;
    const float* bq = bias2 + (size_t)h * NN + qpos;  // + key*256

    // ---- Phase 1: K,V projection (2 accumulators) -> LDS ----
    {
        const bf16_t* wk = wf + (size_t)(1 * 4 + h) * 4096;
        const bf16_t* wv = wf + (size_t)(2 * 4 + h) * 4096;
        f32x16 ak, av;
#pragma unroll
        for (int i = 0; i < 16; i++) { ak[i] = 0.f; av[i] = 0.f; }
#pragma unroll
        for (int ks = 0; ks < 8; ks++) {
            int off = ks * 512 + fro;
            bf16x8 zb = *reinterpret_cast<const bf16x8*>(zg0 + off);
            bf16x8 fk = *reinterpret_cast<const bf16x8*>(wk + off);
            bf16x8 fv = *reinterpret_cast<const bf16x8*>(wv + off);
            ak = __builtin_amdgcn_mfma_f32_32x32x16_bf16(fk, zb, ak, 0, 0, 0);
            av = __builtin_amdgcn_mfma_f32_32x32x16_bf16(fv, zb, av, 0, 0, 0);
        }
        int key0 = w * 32 + rsel;
        bf16x8 f0, f1;
        packX(ak, lo, f0, f1);
        *reinterpret_cast<bf16x8*>(&Kh[key0][hi8]) = f0;
        *reinterpret_cast<bf16x8*>(&Kh[key0][16 + hi8]) = f1;
#pragma unroll
        for (int r = 0; r < 16; r++) {
            int c = (r & 3) + 8 * (r >> 2) + hi4;
            Vt[c][key0] = (bf16_t)av[r];
        }
    }
    __syncthreads();   // K/V visible; Q off the barrier's critical path

    // chunk-0 bias load: overlaps with Q-phase MFMAs
    f32x16 bv;
#pragma unroll
    for (int e = 0; e < 16; e++) {
        int key = 8 * (e >> 2) + hi4 + (e & 3);
        bv[e] = bq[(size_t)key * 256];
    }

    // ---- Phase 2: Q projection only (1 accumulator) ----
    bf16x8 qf0, qf1;
    {
        const bf16_t* wq = wf + (size_t)(0 * 4 + h) * 4096;
        f32x16 aq;
#pragma unroll
        for (int i = 0; i < 16; i++) aq[i] = 0.f;
#pragma unroll
        for (int ks = 0; ks < 8; ks++) {
            int off = ks * 512 + fro;
            bf16x8 zb = *reinterpret_cast<const bf16x8*>(zg0 + off);
            bf16x8 fq = *reinterpret_cast<const bf16x8*>(wq + off);
            aq = __builtin_amdgcn_mfma_f32_32x32x16_bf16(fq, zb, aq, 0, 0, 0);
        }
#pragma unroll
        for (int i = 0; i < 16; i++) aq[i] *= SCL2;
        packX(aq, lo, qf0, qf1);
    }

    // ---- flash attention (max-free): 32 q-rows per wave; s init = bias ----
    f32x16 of;
#pragma unroll
    for (int i = 0; i < 16; i++) of[i] = 0.f;
    float l = 0.f;

#pragma unroll 1
    for (int kt = 0; kt < 8; kt++) {
        bf16x8 k0 = *reinterpret_cast<bf16x8*>(&Kh[kt * 32 + rsel][hi8]);
        bf16x8 k1 = *reinterpret_cast<bf16x8*>(&Kh[kt * 32 + rsel][16 + hi8]);
        __builtin_amdgcn_s_setprio(1);
        f32x16 s = __builtin_amdgcn_mfma_f32_32x32x16_bf16(k0, qf0, bv, 0, 0, 0);
        s = __builtin_amdgcn_mfma_f32_32x32x16_bf16(k1, qf1, s, 0, 0, 0);
        __builtin_amdgcn_s_setprio(0);
        // prefetch next chunk's bias
        if (kt < 7) {
#pragma unroll
            for (int e = 0; e < 16; e++) {
                int key = (kt + 1) * 32 + 8 * (e >> 2) + hi4 + (e & 3);
                bv[e] = bq[(size_t)key * 256];
            }
        }
        // direct exponential (no max subtraction; scores bounded by LN'd inputs)
#pragma unroll
        for (int e = 0; e < 16; e++) s[e] = __builtin_amdgcn_exp2f(s[e]);
        // row sum: packed-f32 tree
        {
            f32x2 a0 = {s[0], s[1]}, a1 = {s[2], s[3]}, a2 = {s[4], s[5]}, a3 = {s[6], s[7]};
            f32x2 a4 = {s[8], s[9]}, a5 = {s[10], s[11]}, a6 = {s[12], s[13]}, a7 = {s[14], s[15]};
            a0 += a1; a2 += a3; a4 += a5; a6 += a7;
            a0 += a2; a4 += a6;
            a0 += a4;
            l += a0[0] + a0[1];
        }
        // P fragments in native C-layout key order (no cross-lane pack)
        bf16x8 pf0 = frag4(pk2(s[0], s[1]), pk2(s[2], s[3]),
                           pk2(s[4], s[5]), pk2(s[6], s[7]));
        bf16x8 pf1 = frag4(pk2(s[8], s[9]), pk2(s[10], s[11]),
                           pk2(s[12], s[13]), pk2(s[14], s[15]));
        // V fragments with the SAME key order: paired b64 reads
        bf16x8 va = cat44(*reinterpret_cast<bf16x4*>(&Vt[rsel][kt * 32 + hi4]),
                          *reinterpret_cast<bf16x4*>(&Vt[rsel][kt * 32 + 8 + hi4]));
        bf16x8 vb = cat44(*reinterpret_cast<bf16x4*>(&Vt[rsel][kt * 32 + 16 + hi4]),
                          *reinterpret_cast<bf16x4*>(&Vt[rsel][kt * 32 + 24 + hi4]));
        __builtin_amdgcn_s_setprio(1);
        of = __builtin_amdgcn_mfma_f32_32x32x16_bf16(va, pf0, of, 0, 0, 0);
        of = __builtin_amdgcn_mfma_f32_32x32x16_bf16(vb, pf1, of, 0, 0, 0);
        __builtin_amdgcn_s_setprio(0);
    }

    l += __shfl_xor(l, 32);
    float linv = 1.0f / l;

    // ---- deferred G projection (1 accumulator), then in-register gating ----
    {
        const bf16_t* wg = wf + (size_t)(3 * 4 + h) * 4096;
        f32x16 ag;
#pragma unroll
        for (int i = 0; i < 16; i++) ag[i] = 0.f;
#pragma unroll
        for (int ks = 0; ks < 8; ks++) {
            int off = ks * 512 + fro;
            bf16x8 zb = *reinterpret_cast<const bf16x8*>(zg0 + off);
            bf16x8 fg = *reinterpret_cast<const bf16x8*>(wg + off);
            ag = __builtin_amdgcn_mfma_f32_32x32x16_bf16(fg, zb, ag, 0, 0, 0);
        }
#pragma unroll
        for (int i = 0; i < 16; i++)
            of[i] = of[i] * linv * (1.0f / (1.0f + __expf(-ag[i])));
    }
    bf16x8 o0, o1;
    packX(of, lo, o0, o1);
    bf16_t* orow = om2 + ((size_t)h * NN + b * 256 + qpos) * 32;
    *reinterpret_cast<bf16x8*>(orow + hi8) = o0;
    *reinterpret_cast<bf16x8*>(orow + 16 + hi8) = o1;
}

// ---------------- final: out = om @ Wo (om pre-gated), fp32 out ----------
__global__ __launch_bounds__(256) void final_kernel(const bf16_t* __restrict__ om2,
                                                    const bf16_t* __restrict__ wfO,
                                                    float* __restrict__ out) {
    __shared__ __align__(16) char smraw[64 * 136 * 2];
    bf16_t(*As)[136] = reinterpret_cast<bf16_t(*)[136]>(smraw);
    float(*Of)[68] = reinterpret_cast<float(*)[68]>(smraw);
    int t = threadIdx.x;
    int rb = blockIdx.x;
#pragma unroll
    for (int i = 0; i < 4; i++) {
        int c = i * 256 + t;
        int r = c >> 4, off = (c & 15) * 8;
        size_t hm = ((size_t)(off >> 5) * NN + rb * 64 + r) * 32 + (off & 31);
        bf16x8 o8 = *reinterpret_cast<const bf16x8*>(&om2[hm]);
        *reinterpret_cast<bf16x8*>(&As[r][off]) = o8;
    }
    __syncthreads();
    int w = t >> 6, lane = t & 63;
    int lx = lane & 15, ly = lane >> 4;
    int m0 = (w >> 1) * 32, n0 = (w & 1) * 32;
    bf16x8 af[2][4];
#pragma unroll
    for (int mt = 0; mt < 2; mt++)
#pragma unroll
        for (int ks = 0; ks < 4; ks++)
            af[mt][ks] = *reinterpret_cast<bf16x8*>(&As[m0 + mt * 16 + lx][ks * 32 + ly * 8]);
    __syncthreads();  // As dead; Of may alias

    for (int half = 0; half < 2; half++) {
        int nc0 = half * 64;
        bf16x8 bfr[2][4];
#pragma unroll
        for (int nt = 0; nt < 2; nt++) {
            int oc = ((nc0 + n0) >> 4) + nt;
#pragma unroll
            for (int ks = 0; ks < 4; ks++)
                bfr[nt][ks] = *reinterpret_cast<const bf16x8*>(
                    &wfO[oc * 2048 + ks * 512 + lx * 32 + ly * 8]);
        }
        f32x4 acc[2][2];
#pragma unroll
        for (int mt = 0; mt < 2; mt++)
#pragma unroll
            for (int nt = 0; nt < 2; nt++) acc[mt][nt] = (f32x4){0.f, 0.f, 0.f, 0.f};
#pragma unroll
        for (int ks = 0; ks < 4; ks++)
#pragma unroll
            for (int mt = 0; mt < 2; mt++)
#pragma unroll
                for (int nt = 0; nt < 2; nt++)
                    acc[mt][nt] = __builtin_amdgcn_mfma_f32_16x16x32_bf16(af[mt][ks], bfr[nt][ks], acc[mt][nt], 0, 0, 0);
#pragma unroll
        for (int mt = 0; mt < 2; mt++)
#pragma unroll
            for (int nt = 0; nt < 2; nt++)
#pragma unroll
                for (int r = 0; r < 4; r++)
                    Of[m0 + mt * 16 + ly * 4 + r][n0 + nt * 16 + lx] = acc[mt][nt][r];
        __syncthreads();
#pragma unroll
        for (int j = 0; j < 4; j++) {
            int ch = j * 256 + t;
            int r = ch >> 4, cb = ch & 15;
            f32x4 val = *reinterpret_cast<f32x4*>(&Of[r][cb * 4]);
            *reinterpret_cast<f32x4*>(&out[(rb * 64 + r) * 128 + nc0 + cb * 4]) = val;
        }
        __syncthreads();
    }
}

extern "C" void kernel_launch(void* const* d_in, const int* in_sizes, int n_in,
                              void* d_out, int out_size, void* d_ws, size_t ws_size,
                              hipStream_t stream) {
    const float* x   = (const float*)d_in[0];
    const float* lnw = (const float*)d_in[1];
    const float* lnb = (const float*)d_in[2];
    const float* Wb  = (const float*)d_in[3];
    const float* Wq  = (const float*)d_in[4];
    const float* Wk  = (const float*)d_in[5];
    const float* Wv  = (const float*)d_in[6];
    const float* Wg  = (const float*)d_in[7];
    const float* Wo  = (const float*)d_in[8];
    float* out = (float*)d_out;

    char* ws = (char*)d_ws;
    const size_t MAT = (size_t)NN * 128 * sizeof(bf16_t);  // 16 MB
    bf16_t* zF    = (bf16_t*)(ws);                           // fragment-ready z
    bf16_t* omat  = (bf16_t*)(ws + MAT);                     // head-major, pre-gated
    bf16_t* wf    = (bf16_t*)(ws + 2 * MAT);                 // 16*4096 bf16 = 128KB
    bf16_t* wfO   = (bf16_t*)(ws + 2 * MAT + (128 << 10));   // 8*2048 bf16 = 32KB
    float*  bias2 = (float*)(ws + 2 * MAT + (1 << 20));      // 1MB

    prep_kernel<<<2072, 256, 0, stream>>>(x, lnw, lnb, Wb, Wq, Wk, Wv, Wg, Wo,
                                          wf, wfO, zF, bias2);
    fat_kernel<<<1024, 512, 0, stream>>>(zF, wf, bias2, omat);
    final_kernel<<<1024, 256, 0, stream>>>(omat, wfO, out);
}

// Round 24
// 64.326 us; speedup vs baseline: 1.1515x; 1.0267x over previous
//
#include <hip/hip_runtime.h>
#include <hip/hip_bf16.h>

#define NN 65536   // N*N rows
#define DD 128
#define NH 4
#define HDIM 32

typedef __bf16 bf16_t;
typedef __bf16 bf16x8 __attribute__((ext_vector_type(8)));
typedef __bf16 bf16x4 __attribute__((ext_vector_type(4)));
typedef __bf16 bf16x2 __attribute__((ext_vector_type(2)));
typedef float f32x2 __attribute__((ext_vector_type(2)));
typedef float f32x4 __attribute__((ext_vector_type(4)));
typedef float f32x16 __attribute__((ext_vector_type(16)));
typedef unsigned int u32;
typedef unsigned int u32x4 __attribute__((ext_vector_type(4)));

__device__ inline u32 pk2(float a, float b) {
    bf16x2 t;
    t[0] = (bf16_t)a;
    t[1] = (bf16_t)b;
    return __builtin_bit_cast(u32, t);
}
__device__ inline bf16x8 frag4(u32 a, u32 b, u32 c, u32 d) {
    u32x4 t = {a, b, c, d};
    return __builtin_bit_cast(bf16x8, t);
}
__device__ inline bf16x8 cat44(bf16x4 a, bf16x4 b) {
    bf16x8 r;
#pragma unroll
    for (int j = 0; j < 4; j++) { r[j] = a[j]; r[4 + j] = b[j]; }
    return r;
}
// VERIFIED (R2-R6): pack C-layout (col=lane&31, c=(r&3)+8*(r>>2)+4*hi) into two
// contiguous frags via shfl. f0 = lane's c[hi*8..+8), f1 = c[16+hi*8..+8).
__device__ inline void packX(const f32x16& s, bool lo, bf16x8& f0, bf16x8& f1) {
    u32 wv[8];
#pragma unroll
    for (int g = 0; g < 4; g++) {
        wv[2 * g] = pk2(s[4 * g], s[4 * g + 1]);
        wv[2 * g + 1] = pk2(s[4 * g + 2], s[4 * g + 3]);
    }
    u32 p0 = __shfl_xor(wv[0], 32), p1 = __shfl_xor(wv[1], 32);
    u32 p2 = __shfl_xor(wv[2], 32), p3 = __shfl_xor(wv[3], 32);
    u32 p4 = __shfl_xor(wv[4], 32), p5 = __shfl_xor(wv[5], 32);
    u32 p6 = __shfl_xor(wv[6], 32), p7 = __shfl_xor(wv[7], 32);
    f0 = frag4(lo ? wv[0] : p2, lo ? wv[1] : p3, lo ? p0 : wv[2], lo ? p1 : wv[3]);
    f1 = frag4(lo ? wv[4] : p6, lo ? wv[5] : p7, lo ? p4 : wv[6], lo ? p5 : wv[7]);
}

// ------- merged prep kernel: blocks 0..23 = weight conversion; 24..2071 = LayerNorm -------
// LN branch writes bias2[h][k][q] DIRECTLY (q = lblk>>3 fixed per block).
__global__ __launch_bounds__(256) void prep_kernel(const float* __restrict__ x,
                                                   const float* __restrict__ lw,
                                                   const float* __restrict__ lb,
                                                   const float* __restrict__ Wb,
                                                   const float* __restrict__ Wq,
                                                   const float* __restrict__ Wk,
                                                   const float* __restrict__ Wv,
                                                   const float* __restrict__ Wg,
                                                   const float* __restrict__ Wo,
                                                   bf16_t* __restrict__ wf,
                                                   bf16_t* __restrict__ wfO,
                                                   bf16_t* __restrict__ zF,
                                                   float* __restrict__ bias2) {
    __shared__ __align__(16) char arena[16896];
    int blk = blockIdx.x, t = threadIdx.x;
    if (blk < 16) {
        float(*Ws)[33] = reinterpret_cast<float(*)[33]>(arena);
        int m = blk >> 2, h = blk & 3;
        const float* W = (m == 0) ? Wq : (m == 1) ? Wk : (m == 2) ? Wv : Wg;
#pragma unroll
        for (int p = 0; p < 16; p++) {
            int d = p * 8 + (t >> 5), o = t & 31;
            Ws[d][o] = W[d * 128 + h * 32 + o];
        }
        __syncthreads();
        bf16_t* dst = wf + (size_t)blk * 4096;
#pragma unroll
        for (int p = 0; p < 16; p++) {
            int j = p * 256 + t;
            int ks = j >> 9, rsel = (j >> 4) & 31, e = j & 15;
            dst[j] = (bf16_t)Ws[ks * 16 + e][rsel];
        }
        return;
    }
    if (blk < 24) {
        float(*Ws2)[17] = reinterpret_cast<float(*)[17]>(arena);
        int oc = blk - 16;  // 0..7
#pragma unroll
        for (int p = 0; p < 8; p++) {
            int d = p * 16 + (t >> 4), o = t & 15;
            Ws2[d][o] = Wo[d * 128 + oc * 16 + o];
        }
        __syncthreads();
        bf16_t* dst = wfO + (size_t)oc * 2048;
#pragma unroll
        for (int p = 0; p < 8; p++) {
            int j = p * 256 + t;
            int ks = j >> 9, rem = j & 511;
            int lx = rem >> 5, ly = (rem >> 3) & 3, e = j & 7;
            dst[j] = (bf16_t)Ws2[ks * 32 + ly * 8 + e][lx];
        }
        return;
    }
    // ---- LayerNorm + fused bias; z emitted in fragment-ready zF layout ----
    bf16_t* zs = reinterpret_cast<bf16_t*>(arena);            // 8KB [ks][rsel][16]
    float(*bias_s)[32] = reinterpret_cast<float(*)[32]>(arena + 8192);
    int lblk = blk - 24;
    int g = t >> 5, l32 = t & 31;
    int rowbase = lblk * 32;
    int d0 = l32 * 4;
    f32x4 lwv = *reinterpret_cast<const f32x4*>(&lw[d0]);
    f32x4 lbv = *reinterpret_cast<const f32x4*>(&lb[d0]);
    f32x4 wbj[4];
#pragma unroll
    for (int j = 0; j < 4; j++) wbj[j] = *reinterpret_cast<const f32x4*>(&Wb[(d0 + j) * 4]);
#pragma unroll
    for (int r4 = 0; r4 < 4; r4++) {
        int roff = r4 * 8 + g;
        int row = rowbase + roff;
        f32x4 v = *reinterpret_cast<const f32x4*>(&x[(size_t)row * 128 + d0]);
        float s1 = v[0] + v[1] + v[2] + v[3];
        float s2 = v[0] * v[0] + v[1] * v[1] + v[2] * v[2] + v[3] * v[3];
#pragma unroll
        for (int m = 1; m < 32; m <<= 1) {
            s1 += __shfl_xor(s1, m);
            s2 += __shfl_xor(s2, m);
        }
        float mu = s1 * (1.0f / 128.0f);
        float var = s2 * (1.0f / 128.0f) - mu * mu;
        float rs = rsqrtf(var + 1e-5f);
        float zv[4];
        bf16x4 pk;
#pragma unroll
        for (int j = 0; j < 4; j++) {
            zv[j] = (v[j] - mu) * rs * lwv[j] + lbv[j];
            pk[j] = (bf16_t)zv[j];
        }
        *reinterpret_cast<bf16x4*>(&zs[(l32 >> 2) * 512 + roff * 16 + (l32 & 3) * 4]) = pk;
        f32x4 pb = {0.f, 0.f, 0.f, 0.f};
#pragma unroll
        for (int j = 0; j < 4; j++)
#pragma unroll
            for (int hh = 0; hh < 4; hh++) pb[hh] += zv[j] * wbj[j][hh];
#pragma unroll
        for (int m = 1; m < 32; m <<= 1) {
#pragma unroll
            for (int hh = 0; hh < 4; hh++) pb[hh] += __shfl_xor(pb[hh], m);
        }
        if (l32 == 0) {
#pragma unroll
            for (int hh = 0; hh < 4; hh++)
                bias_s[hh][roff] = pb[hh] * 1.4426950408889634f;
        }
    }
    __syncthreads();
    if (t < 128) {
        // direct transposed write: bias2[h][k][q], q fixed per block
        int hh = t >> 5, rl = t & 31;
        int q = lblk >> 3, k = ((lblk & 7) << 5) + rl;
        bias2[(size_t)hh * NN + (size_t)k * 256 + q] = bias_s[hh][rl];
    }
    bf16_t* dst = zF + (size_t)lblk * 4096;
#pragma unroll
    for (int p = 0; p < 2; p++) {
        int c = p * 2048 + t * 8;
        *reinterpret_cast<bf16x8*>(dst + c) = *reinterpret_cast<bf16x8*>(zs + c);
    }
}

// ---------- fused QKV projection + flash attention per (b,h), 8-wave blocks ----------
// Single 3-accumulator projection loop {K,V,Q} (one zb stream, 48 acc regs);
// G deferred post-loop (keeps attention-loop live set minimal). Max-free
// softmax, kt-loop at unroll 1 (R19/R21: more unroll -> scratch spill).
__global__ __launch_bounds__(512, 4) void fat_kernel(const bf16_t* __restrict__ zF,
                                                     const bf16_t* __restrict__ wf,
                                                     const float* __restrict__ bias2,
                                                     bf16_t* __restrict__ om2) {
    __shared__ bf16_t Kh[256][44];   // [key][c] padded -> conflict-free b128
    __shared__ bf16_t Vt[32][268];   // [c][key] padded -> 2-way b64 (free)
    int t = threadIdx.x;
    int id = blockIdx.x;
    int h = (id >> 3) & 3;
    int b = (id & 7) + (id >> 5) * 8;
    int w = t >> 6, lane = t & 63;
    int rsel = lane & 31, hi = lane >> 5;
    int hi8 = hi * 8, hi4 = hi * 4;
    bool lo = (hi == 0);
    const float SCL2 = 0.17677669529663687f * 1.4426950408889634f;  // scale * log2(e)
    const bf16_t* zg0 = zF + (size_t)(b * 8 + w) * 4096;  // this wave's 32-row group
    int fro = rsel * 16 + hi8;
    int qpos = w * 32 + rsel;
    const float* bq = bias2 + (size_t)h * NN + qpos;  // + key*256

    // ---- fused K,V,Q projection (3 accumulators) ----
    bf16x8 qf0, qf1;
    {
        const bf16_t* wq = wf + (size_t)(0 * 4 + h) * 4096;
        const bf16_t* wk = wf + (size_t)(1 * 4 + h) * 4096;
        const bf16_t* wv = wf + (size_t)(2 * 4 + h) * 4096;
        f32x16 ak, av, aq;
#pragma unroll
        for (int i = 0; i < 16; i++) { ak[i] = 0.f; av[i] = 0.f; aq[i] = 0.f; }
#pragma unroll
        for (int ks = 0; ks < 8; ks++) {
            int off = ks * 512 + fro;
            bf16x8 zb = *reinterpret_cast<const bf16x8*>(zg0 + off);
            bf16x8 fk = *reinterpret_cast<const bf16x8*>(wk + off);
            bf16x8 fv = *reinterpret_cast<const bf16x8*>(wv + off);
            bf16x8 fq = *reinterpret_cast<const bf16x8*>(wq + off);
            ak = __builtin_amdgcn_mfma_f32_32x32x16_bf16(fk, zb, ak, 0, 0, 0);
            av = __builtin_amdgcn_mfma_f32_32x32x16_bf16(fv, zb, av, 0, 0, 0);
            aq = __builtin_amdgcn_mfma_f32_32x32x16_bf16(fq, zb, aq, 0, 0, 0);
        }
        int key0 = w * 32 + rsel;
        bf16x8 f0, f1;
        packX(ak, lo, f0, f1);
        *reinterpret_cast<bf16x8*>(&Kh[key0][hi8]) = f0;
        *reinterpret_cast<bf16x8*>(&Kh[key0][16 + hi8]) = f1;
#pragma unroll
        for (int r = 0; r < 16; r++) {
            int c = (r & 3) + 8 * (r >> 2) + hi4;
            Vt[c][key0] = (bf16_t)av[r];
        }
#pragma unroll
        for (int i = 0; i < 16; i++) aq[i] *= SCL2;
        packX(aq, lo, qf0, qf1);
    }
    // chunk-0 bias load: overlaps LDS stores + barrier wait
    f32x16 bv;
#pragma unroll
    for (int e = 0; e < 16; e++) {
        int key = 8 * (e >> 2) + hi4 + (e & 3);
        bv[e] = bq[(size_t)key * 256];
    }
    __syncthreads();   // K/V visible to all waves

    // ---- flash attention (max-free): 32 q-rows per wave; s init = bias ----
    f32x16 of;
#pragma unroll
    for (int i = 0; i < 16; i++) of[i] = 0.f;
    float l = 0.f;

#pragma unroll 1
    for (int kt = 0; kt < 8; kt++) {
        bf16x8 k0 = *reinterpret_cast<bf16x8*>(&Kh[kt * 32 + rsel][hi8]);
        bf16x8 k1 = *reinterpret_cast<bf16x8*>(&Kh[kt * 32 + rsel][16 + hi8]);
        __builtin_amdgcn_s_setprio(1);
        f32x16 s = __builtin_amdgcn_mfma_f32_32x32x16_bf16(k0, qf0, bv, 0, 0, 0);
        s = __builtin_amdgcn_mfma_f32_32x32x16_bf16(k1, qf1, s, 0, 0, 0);
        __builtin_amdgcn_s_setprio(0);
        // prefetch next chunk's bias
        if (kt < 7) {
#pragma unroll
            for (int e = 0; e < 16; e++) {
                int key = (kt + 1) * 32 + 8 * (e >> 2) + hi4 + (e & 3);
                bv[e] = bq[(size_t)key * 256];
            }
        }
        // direct exponential (no max subtraction; scores bounded by LN'd inputs)
#pragma unroll
        for (int e = 0; e < 16; e++) s[e] = __builtin_amdgcn_exp2f(s[e]);
        // row sum: packed-f32 tree
        {
            f32x2 a0 = {s[0], s[1]}, a1 = {s[2], s[3]}, a2 = {s[4], s[5]}, a3 = {s[6], s[7]};
            f32x2 a4 = {s[8], s[9]}, a5 = {s[10], s[11]}, a6 = {s[12], s[13]}, a7 = {s[14], s[15]};
            a0 += a1; a2 += a3; a4 += a5; a6 += a7;
            a0 += a2; a4 += a6;
            a0 += a4;
            l += a0[0] + a0[1];
        }
        // P fragments in native C-layout key order (no cross-lane pack)
        bf16x8 pf0 = frag4(pk2(s[0], s[1]), pk2(s[2], s[3]),
                           pk2(s[4], s[5]), pk2(s[6], s[7]));
        bf16x8 pf1 = frag4(pk2(s[8], s[9]), pk2(s[10], s[11]),
                           pk2(s[12], s[13]), pk2(s[14], s[15]));
        // V fragments with the SAME key order: paired b64 reads
        bf16x8 va = cat44(*reinterpret_cast<bf16x4*>(&Vt[rsel][kt * 32 + hi4]),
                          *reinterpret_cast<bf16x4*>(&Vt[rsel][kt * 32 + 8 + hi4]));
        bf16x8 vb = cat44(*reinterpret_cast<bf16x4*>(&Vt[rsel][kt * 32 + 16 + hi4]),
                          *reinterpret_cast<bf16x4*>(&Vt[rsel][kt * 32 + 24 + hi4]));
        __builtin_amdgcn_s_setprio(1);
        of = __builtin_amdgcn_mfma_f32_32x32x16_bf16(va, pf0, of, 0, 0, 0);
        of = __builtin_amdgcn_mfma_f32_32x32x16_bf16(vb, pf1, of, 0, 0, 0);
        __builtin_amdgcn_s_setprio(0);
    }

    l += __shfl_xor(l, 32);
    float linv = 1.0f / l;

    // ---- deferred G projection (1 accumulator), then in-register gating ----
    {
        const bf16_t* wg = wf + (size_t)(3 * 4 + h) * 4096;
        f32x16 ag;
#pragma unroll
        for (int i = 0; i < 16; i++) ag[i] = 0.f;
#pragma unroll
        for (int ks = 0; ks < 8; ks++) {
            int off = ks * 512 + fro;
            bf16x8 zb = *reinterpret_cast<const bf16x8*>(zg0 + off);
            bf16x8 fg = *reinterpret_cast<const bf16x8*>(wg + off);
            ag = __builtin_amdgcn_mfma_f32_32x32x16_bf16(fg, zb, ag, 0, 0, 0);
        }
#pragma unroll
        for (int i = 0; i < 16; i++)
            of[i] = of[i] * linv * (1.0f / (1.0f + __expf(-ag[i])));
    }
    bf16x8 o0, o1;
    packX(of, lo, o0, o1);
    bf16_t* orow = om2 + ((size_t)h * NN + b * 256 + qpos) * 32;
    *reinterpret_cast<bf16x8*>(orow + hi8) = o0;
    *reinterpret_cast<bf16x8*>(orow + 16 + hi8) = o1;
}

// ---------------- final: out = om @ Wo (om pre-gated), fp32 out ----------
__global__ __launch_bounds__(256) void final_kernel(const bf16_t* __restrict__ om2,
                                                    const bf16_t* __restrict__ wfO,
                                                    float* __restrict__ out) {
    __shared__ __align__(16) char smraw[64 * 136 * 2];
    bf16_t(*As)[136] = reinterpret_cast<bf16_t(*)[136]>(smraw);
    float(*Of)[68] = reinterpret_cast<float(*)[68]>(smraw);
    int t = threadIdx.x;
    int rb = blockIdx.x;
#pragma unroll
    for (int i = 0; i < 4; i++) {
        int c = i * 256 + t;
        int r = c >> 4, off = (c & 15) * 8;
        size_t hm = ((size_t)(off >> 5) * NN + rb * 64 + r) * 32 + (off & 31);
        bf16x8 o8 = *reinterpret_cast<const bf16x8*>(&om2[hm]);
        *reinterpret_cast<bf16x8*>(&As[r][off]) = o8;
    }
    __syncthreads();
    int w = t >> 6, lane = t & 63;
    int lx = lane & 15, ly = lane >> 4;
    int m0 = (w >> 1) * 32, n0 = (w & 1) * 32;
    bf16x8 af[2][4];
#pragma unroll
    for (int mt = 0; mt < 2; mt++)
#pragma unroll
        for (int ks = 0; ks < 4; ks++)
            af[mt][ks] = *reinterpret_cast<bf16x8*>(&As[m0 + mt * 16 + lx][ks * 32 + ly * 8]);
    __syncthreads();  // As dead; Of may alias

    for (int half = 0; half < 2; half++) {
        int nc0 = half * 64;
        bf16x8 bfr[2][4];
#pragma unroll
        for (int nt = 0; nt < 2; nt++) {
            int oc = ((nc0 + n0) >> 4) + nt;
#pragma unroll
            for (int ks = 0; ks < 4; ks++)
                bfr[nt][ks] = *reinterpret_cast<const bf16x8*>(
                    &wfO[oc * 2048 + ks * 512 + lx * 32 + ly * 8]);
        }
        f32x4 acc[2][2];
#pragma unroll
        for (int mt = 0; mt < 2; mt++)
#pragma unroll
            for (int nt = 0; nt < 2; nt++) acc[mt][nt] = (f32x4){0.f, 0.f, 0.f, 0.f};
#pragma unroll
        for (int ks = 0; ks < 4; ks++)
#pragma unroll
            for (int mt = 0; mt < 2; mt++)
#pragma unroll
                for (int nt = 0; nt < 2; nt++)
                    acc[mt][nt] = __builtin_amdgcn_mfma_f32_16x16x32_bf16(af[mt][ks], bfr[nt][ks], acc[mt][nt], 0, 0, 0);
#pragma unroll
        for (int mt = 0; mt < 2; mt++)
#pragma unroll
            for (int nt = 0; nt < 2; nt++)
#pragma unroll
                for (int r = 0; r < 4; r++)
                    Of[m0 + mt * 16 + ly * 4 + r][n0 + nt * 16 + lx] = acc[mt][nt][r];
        __syncthreads();
#pragma unroll
        for (int j = 0; j < 4; j++) {
            int ch = j * 256 + t;
            int r = ch >> 4, cb = ch & 15;
            f32x4 val = *reinterpret_cast<f32x4*>(&Of[r][cb * 4]);
            *reinterpret_cast<f32x4*>(&out[(rb * 64 + r) * 128 + nc0 + cb * 4]) = val;
        }
        __syncthreads();
    }
}

extern "C" void kernel_launch(void* const* d_in, const int* in_sizes, int n_in,
                              void* d_out, int out_size, void* d_ws, size_t ws_size,
                              hipStream_t stream) {
    const float* x   = (const float*)d_in[0];
    const float* lnw = (const float*)d_in[1];
    const float* lnb = (const float*)d_in[2];
    const float* Wb  = (const float*)d_in[3];
    const float* Wq  = (const float*)d_in[4];
    const float* Wk  = (const float*)d_in[5];
    const float* Wv  = (const float*)d_in[6];
    const float* Wg  = (const float*)d_in[7];
    const float* Wo  = (const float*)d_in[8];
    float* out = (float*)d_out;

    char* ws = (char*)d_ws;
    const size_t MAT = (size_t)NN * 128 * sizeof(bf16_t);  // 16 MB
    bf16_t* zF    = (bf16_t*)(ws);                           // fragment-ready z
    bf16_t* omat  = (bf16_t*)(ws + MAT);                     // head-major, pre-gated
    bf16_t* wf    = (bf16_t*)(ws + 2 * MAT);                 // 16*4096 bf16 = 128KB
    bf16_t* wfO   = (bf16_t*)(ws + 2 * MAT + (128 << 10));   // 8*2048 bf16 = 32KB
    float*  bias2 = (float*)(ws + 2 * MAT + (1 << 20));      // 1MB

    prep_kernel<<<2072, 256, 0, stream>>>(x, lnw, lnb, Wb, Wq, Wk, Wv, Wg, Wo,
                                          wf, wfO, zF, bias2);
    fat_kernel<<<1024, 512, 0, stream>>>(zF, wf, bias2, omat);
    final_kernel<<<1024, 256, 0, stream>>>(omat, wfO, out);
}